// Round 1
// baseline (10826.981 us; speedup 1.0000x reference)
//
#include <hip/hip_runtime.h>
#include <math.h>

#define Bsz 512
#define Fsz 64
#define Hsz 256
#define TSTEPS 128
#define G3 (3*Hsz)

#define BT 32            // batch rows per block
#define HT 16            // hidden cols per block
#define GB 48            // gate rows per block (3*HT)
#define HB 16            // hidden blocks
#define BG 16            // batch groups
#define NBLK (BG*HB)     // 256
#define NTHR 256
#define CNT_STRIDE 512

#define WPAD 260         // padded LDS row stride (K=256)
#define XPAD 68          // padded LDS row stride (K=64)

// LDS layout (floats)
#define OFF_WHH 0
#define OFF_AUX (GB*WPAD)            // decoder: M slice; encoder: wih + x tiles
#define OFF_H   (2*GB*WPAD)
#define OFF_RW  (OFF_H + BT*WPAD)
#define OFF_B1  (OFF_RW + 4*WPAD)
#define OFF_B2  (OFF_B1 + GB)
#define OFF_B3  (OFF_B2 + GB)
#define LDS_FLOATS (OFF_B3 + 8)
#define SMEM_BYTES (LDS_FLOATS*4)    // ~137.7 KB -> 1 block/CU

__device__ __forceinline__ int grow(int lr, int hb) {
    return (lr >> 4)*Hsz + hb*HT + (lr & 15);   // gate*256 + hb*16 + j
}
__device__ __forceinline__ void fma4(float& a, float4 x, float4 y) {
    a += x.x*y.x; a += x.y*y.y; a += x.z*y.z; a += x.w*y.w;
}
__device__ __forceinline__ float sigmoidf_(float v) { return 1.0f/(1.0f + expf(-v)); }

// ---------------- setup: M = dec_Wih@reg_W, cfold = dec_Wih@reg_b + dec_bih,
// ---------------- gi0 = x[:,127,:]@dec_Wih.T + dec_bih
extern "C" __global__ void gru_setup(const float* __restrict__ x,
                                     const float* __restrict__ dWih,
                                     const float* __restrict__ dbih,
                                     const float* __restrict__ regW,
                                     const float* __restrict__ regb,
                                     float* __restrict__ Mw,
                                     float* __restrict__ cfold,
                                     float* __restrict__ gi0)
{
    int idx = blockIdx.x*blockDim.x + threadIdx.x;
    if (idx < G3*Hsz) {
        int g = idx >> 8, j = idx & 255;
        float a = 0.f;
        #pragma unroll 8
        for (int f = 0; f < Fsz; ++f) a += dWih[g*Fsz + f]*regW[f*Hsz + j];
        Mw[idx] = a;
    } else if (idx < G3*Hsz + G3) {
        int g = idx - G3*Hsz;
        float a = dbih[g];
        #pragma unroll 8
        for (int f = 0; f < Fsz; ++f) a += dWih[g*Fsz + f]*regb[f];
        cfold[g] = a;
    } else {
        int e = idx - (G3*Hsz + G3);
        if (e < Bsz*G3) {
            int b = e / G3, g = e - b*G3;
            const float* xp = x + (size_t)b*(256*64) + 127*64;
            float a = dbih[g];
            #pragma unroll 8
            for (int f = 0; f < Fsz; ++f) a += xp[f]*dWih[g*Fsz + f];
            gi0[e] = a;
        }
    }
}

// ---------------- persistent GRU kernel ----------------
extern "C" __global__ void __launch_bounds__(NTHR, 1)
gru_persistent(const float* __restrict__ x,
               const float* __restrict__ eWih, const float* __restrict__ eWhh,
               const float* __restrict__ ebih, const float* __restrict__ ebhh,
               const float* __restrict__ dWhh, const float* __restrict__ dbhh,
               const float* __restrict__ Mw,   const float* __restrict__ cfold,
               const float* __restrict__ gi0,  const float* __restrict__ regW,
               const float* __restrict__ regb,
               float* __restrict__ hbuf, int* __restrict__ cnt,
               float* __restrict__ out)
{
    extern __shared__ float lds[];
    const int tid = threadIdx.x;
    const int blk = blockIdx.x;
    const int bg  = blk >> 4;
    const int hb  = blk & 15;
    const int tg  = tid & 15;
    const int tb  = tid >> 4;
    const int hcol = hb*HT + tg;

    float* s_whh = lds + OFF_WHH;   // [48][260]
    float* s_aux = lds + OFF_AUX;   // decoder: M [48][260]
    float* s_wih = s_aux;           // encoder: [48][68]
    float* s_x   = s_aux + GB*XPAD; // encoder: [32][68]
    float* s_h   = lds + OFF_H;     // [32][260]
    float* s_rw  = lds + OFF_RW;    // [4][260]
    float* s_b1  = lds + OFF_B1;    // 48: bih (enc) / cfold (dec)
    float* s_b2  = lds + OFF_B2;    // 48: bhh
    float* s_b3  = lds + OFF_B3;    // 4: reg_b slice

    int* mycnt = cnt + bg*CNT_STRIDE;

    // ---- stage encoder weights (once) ----
    for (int idx = tid; idx < GB*64; idx += NTHR) {
        int lr = idx >> 6, c4 = idx & 63;
        *(float4*)(s_whh + lr*WPAD + c4*4) =
            *(const float4*)(eWhh + (size_t)grow(lr,hb)*Hsz + c4*4);
    }
    for (int idx = tid; idx < GB*16; idx += NTHR) {
        int lr = idx >> 4, c4 = idx & 15;
        *(float4*)(s_wih + lr*XPAD + c4*4) =
            *(const float4*)(eWih + (size_t)grow(lr,hb)*Fsz + c4*4);
    }
    if (tid < GB) { int g = grow(tid,hb); s_b1[tid] = ebih[g]; s_b2[tid] = ebhh[g]; }
    __syncthreads();

    int parity = 0;

    // =================== ENCODER ===================
    for (int s = 0; s < TSTEPS; ++s) {
        if (s > 0) {
            if (tid == 0) {
                while (__hip_atomic_load(mycnt + s, __ATOMIC_ACQUIRE,
                                         __HIP_MEMORY_SCOPE_AGENT) < HB)
                    __builtin_amdgcn_s_sleep(1);
            }
            __syncthreads();
        }
        const float* hin = hbuf + (size_t)parity*Bsz*Hsz;
        for (int idx = tid; idx < BT*64; idx += NTHR) {
            int r = idx >> 6, c4 = idx & 63;
            *(float4*)(s_h + r*WPAD + c4*4) =
                *(const float4*)(hin + (size_t)(bg*BT + r)*Hsz + c4*4);
        }
        for (int idx = tid; idx < BT*16; idx += NTHR) {
            int r = idx >> 4, c4 = idx & 15;
            *(float4*)(s_x + r*XPAD + c4*4) =
                *(const float4*)(x + (size_t)(bg*BT + r)*(256*64) + s*Fsz + c4*4);
        }
        __syncthreads();

        float aH0=0,aH1=0,aH2=0,aH3=0,aH4=0,aH5=0;
        {
            const float4* h0p = (const float4*)(s_h + (2*tb)*WPAD);
            const float4* h1p = (const float4*)(s_h + (2*tb+1)*WPAD);
            const float4* w0p = (const float4*)(s_whh + tg*WPAD);
            const float4* w1p = (const float4*)(s_whh + (tg+16)*WPAD);
            const float4* w2p = (const float4*)(s_whh + (tg+32)*WPAD);
            #pragma unroll 8
            for (int k = 0; k < 64; ++k) {
                float4 h0 = h0p[k], h1 = h1p[k];
                float4 w0 = w0p[k], w1 = w1p[k], w2 = w2p[k];
                fma4(aH0,h0,w0); fma4(aH1,h0,w1); fma4(aH2,h0,w2);
                fma4(aH3,h1,w0); fma4(aH4,h1,w1); fma4(aH5,h1,w2);
            }
        }
        float aI0=0,aI1=0,aI2=0,aI3=0,aI4=0,aI5=0;
        {
            const float4* x0p = (const float4*)(s_x + (2*tb)*XPAD);
            const float4* x1p = (const float4*)(s_x + (2*tb+1)*XPAD);
            const float4* u0p = (const float4*)(s_wih + tg*XPAD);
            const float4* u1p = (const float4*)(s_wih + (tg+16)*XPAD);
            const float4* u2p = (const float4*)(s_wih + (tg+32)*XPAD);
            #pragma unroll
            for (int k = 0; k < 16; ++k) {
                float4 x0 = x0p[k], x1 = x1p[k];
                float4 u0 = u0p[k], u1 = u1p[k], u2 = u2p[k];
                fma4(aI0,x0,u0); fma4(aI1,x0,u1); fma4(aI2,x0,u2);
                fma4(aI3,x1,u0); fma4(aI4,x1,u1); fma4(aI5,x1,u2);
            }
        }
        float* hout = hbuf + (size_t)(parity^1)*Bsz*Hsz;
        {
            float biR = s_b1[tg], biZ = s_b1[tg+16], biN = s_b1[tg+32];
            float bhR = s_b2[tg], bhZ = s_b2[tg+16], bhN = s_b2[tg+32];
            float r0 = sigmoidf_(aI0 + biR + aH0 + bhR);
            float z0 = sigmoidf_(aI1 + biZ + aH1 + bhZ);
            float n0 = tanhf(aI2 + biN + r0*(aH2 + bhN));
            float ho0 = s_h[(2*tb)*WPAD + hcol];
            hout[(size_t)(bg*BT + 2*tb)*Hsz + hcol] = (1.0f - z0)*n0 + z0*ho0;
            float r1 = sigmoidf_(aI3 + biR + aH3 + bhR);
            float z1 = sigmoidf_(aI4 + biZ + aH4 + bhZ);
            float n1 = tanhf(aI5 + biN + r1*(aH5 + bhN));
            float ho1 = s_h[(2*tb+1)*WPAD + hcol];
            hout[(size_t)(bg*BT + 2*tb+1)*Hsz + hcol] = (1.0f - z1)*n1 + z1*ho1;
        }
        __threadfence();
        __syncthreads();
        if (tid == 0)
            __hip_atomic_fetch_add(mycnt + s + 1, 1, __ATOMIC_RELEASE,
                                   __HIP_MEMORY_SCOPE_AGENT);
        parity ^= 1;
    }

    // ---- stage decoder weights ----
    for (int idx = tid; idx < GB*64; idx += NTHR) {
        int lr = idx >> 6, c4 = idx & 63;
        *(float4*)(s_whh + lr*WPAD + c4*4) =
            *(const float4*)(dWhh + (size_t)grow(lr,hb)*Hsz + c4*4);
        *(float4*)(s_aux + lr*WPAD + c4*4) =
            *(const float4*)(Mw + (size_t)grow(lr,hb)*Hsz + c4*4);
    }
    {
        int r = tid >> 6, c4 = tid & 63;
        *(float4*)(s_rw + r*WPAD + c4*4) =
            *(const float4*)(regW + (size_t)(hb*4 + r)*Hsz + c4*4);
    }
    if (tid < GB) { int g = grow(tid,hb); s_b1[tid] = cfold[g]; s_b2[tid] = dbhh[g]; }
    if (tid < 4) s_b3[tid] = regb[hb*4 + tid];
    __syncthreads();

    // =================== DECODER ===================
    for (int i = 0; i < TSTEPS; ++i) {
        const int s = TSTEPS + i;
        if (tid == 0) {
            while (__hip_atomic_load(mycnt + s, __ATOMIC_ACQUIRE,
                                     __HIP_MEMORY_SCOPE_AGENT) < HB)
                __builtin_amdgcn_s_sleep(1);
        }
        __syncthreads();
        const float* hin = hbuf + (size_t)parity*Bsz*Hsz;
        for (int idx = tid; idx < BT*64; idx += NTHR) {
            int r = idx >> 6, c4 = idx & 63;
            *(float4*)(s_h + r*WPAD + c4*4) =
                *(const float4*)(hin + (size_t)(bg*BT + r)*Hsz + c4*4);
        }
        __syncthreads();

        float aH0=0,aH1=0,aH2=0,aH3=0,aH4=0,aH5=0;
        float aI0=0,aI1=0,aI2=0,aI3=0,aI4=0,aI5=0;
        if (i == 0) {
            const float* gp0 = gi0 + (size_t)(bg*BT + 2*tb)*G3;
            const float* gp1 = gp0 + G3;
            aI0 = gp0[hcol]; aI1 = gp0[256+hcol]; aI2 = gp0[512+hcol];
            aI3 = gp1[hcol]; aI4 = gp1[256+hcol]; aI5 = gp1[512+hcol];
            const float4* h0p = (const float4*)(s_h + (2*tb)*WPAD);
            const float4* h1p = (const float4*)(s_h + (2*tb+1)*WPAD);
            const float4* w0p = (const float4*)(s_whh + tg*WPAD);
            const float4* w1p = (const float4*)(s_whh + (tg+16)*WPAD);
            const float4* w2p = (const float4*)(s_whh + (tg+32)*WPAD);
            #pragma unroll 8
            for (int k = 0; k < 64; ++k) {
                float4 h0 = h0p[k], h1 = h1p[k];
                float4 w0 = w0p[k], w1 = w1p[k], w2 = w2p[k];
                fma4(aH0,h0,w0); fma4(aH1,h0,w1); fma4(aH2,h0,w2);
                fma4(aH3,h1,w0); fma4(aH4,h1,w1); fma4(aH5,h1,w2);
            }
        } else {
            const float4* h0p = (const float4*)(s_h + (2*tb)*WPAD);
            const float4* h1p = (const float4*)(s_h + (2*tb+1)*WPAD);
            const float4* w0p = (const float4*)(s_whh + tg*WPAD);
            const float4* w1p = (const float4*)(s_whh + (tg+16)*WPAD);
            const float4* w2p = (const float4*)(s_whh + (tg+32)*WPAD);
            const float4* m0p = (const float4*)(s_aux + tg*WPAD);
            const float4* m1p = (const float4*)(s_aux + (tg+16)*WPAD);
            const float4* m2p = (const float4*)(s_aux + (tg+32)*WPAD);
            #pragma unroll 4
            for (int k = 0; k < 64; ++k) {
                float4 h0 = h0p[k], h1 = h1p[k];
                float4 w0 = w0p[k], w1 = w1p[k], w2 = w2p[k];
                float4 m0 = m0p[k], m1 = m1p[k], m2 = m2p[k];
                fma4(aH0,h0,w0); fma4(aH1,h0,w1); fma4(aH2,h0,w2);
                fma4(aH3,h1,w0); fma4(aH4,h1,w1); fma4(aH5,h1,w2);
                fma4(aI0,h0,m0); fma4(aI1,h0,m1); fma4(aI2,h0,m2);
                fma4(aI3,h1,m0); fma4(aI4,h1,m1); fma4(aI5,h1,m2);
            }
        }

        // out_{i-1} = h^d_i @ reg_W.T + reg_b  (this block's 4 f-columns)
        if (i >= 1 && tid < 128) {
            int bl = tid >> 2, fl = tid & 3;
            const float4* hp = (const float4*)(s_h + bl*WPAD);
            const float4* wp = (const float4*)(s_rw + fl*WPAD);
            float acc = s_b3[fl];
            #pragma unroll 8
            for (int k = 0; k < 64; ++k) fma4(acc, hp[k], wp[k]);
            out[(size_t)(bg*BT + bl)*(TSTEPS*Fsz) + (size_t)(i-1)*Fsz + hb*4 + fl] = acc;
        }

        float* hout = hbuf + (size_t)(parity^1)*Bsz*Hsz;
        {
            float biR = (i==0)?0.f:s_b1[tg];
            float biZ = (i==0)?0.f:s_b1[tg+16];
            float biN = (i==0)?0.f:s_b1[tg+32];
            float bhR = s_b2[tg], bhZ = s_b2[tg+16], bhN = s_b2[tg+32];
            float r0 = sigmoidf_(aI0 + biR + aH0 + bhR);
            float z0 = sigmoidf_(aI1 + biZ + aH1 + bhZ);
            float n0 = tanhf(aI2 + biN + r0*(aH2 + bhN));
            float ho0 = s_h[(2*tb)*WPAD + hcol];
            hout[(size_t)(bg*BT + 2*tb)*Hsz + hcol] = (1.0f - z0)*n0 + z0*ho0;
            float r1 = sigmoidf_(aI3 + biR + aH3 + bhR);
            float z1 = sigmoidf_(aI4 + biZ + aH4 + bhZ);
            float n1 = tanhf(aI5 + biN + r1*(aH5 + bhN));
            float ho1 = s_h[(2*tb+1)*WPAD + hcol];
            hout[(size_t)(bg*BT + 2*tb+1)*Hsz + hcol] = (1.0f - z1)*n1 + z1*ho1;
        }
        __threadfence();
        __syncthreads();
        if (tid == 0)
            __hip_atomic_fetch_add(mycnt + s + 1, 1, __ATOMIC_RELEASE,
                                   __HIP_MEMORY_SCOPE_AGENT);
        parity ^= 1;
    }

    // ---- final out_{127} from h^d_128 ----
    {
        const int s = 2*TSTEPS;
        if (tid == 0) {
            while (__hip_atomic_load(mycnt + s, __ATOMIC_ACQUIRE,
                                     __HIP_MEMORY_SCOPE_AGENT) < HB)
                __builtin_amdgcn_s_sleep(1);
        }
        __syncthreads();
        const float* hin = hbuf + (size_t)parity*Bsz*Hsz;
        for (int idx = tid; idx < BT*64; idx += NTHR) {
            int r = idx >> 6, c4 = idx & 63;
            *(float4*)(s_h + r*WPAD + c4*4) =
                *(const float4*)(hin + (size_t)(bg*BT + r)*Hsz + c4*4);
        }
        __syncthreads();
        if (tid < 128) {
            int bl = tid >> 2, fl = tid & 3;
            const float4* hp = (const float4*)(s_h + bl*WPAD);
            const float4* wp = (const float4*)(s_rw + fl*WPAD);
            float acc = s_b3[fl];
            #pragma unroll 8
            for (int k = 0; k < 64; ++k) fma4(acc, hp[k], wp[k]);
            out[(size_t)(bg*BT + bl)*(TSTEPS*Fsz) + (size_t)(TSTEPS-1)*Fsz + hb*4 + fl] = acc;
        }
    }
}

extern "C" void kernel_launch(void* const* d_in, const int* in_sizes, int n_in,
                              void* d_out, int out_size, void* d_ws, size_t ws_size,
                              hipStream_t stream)
{
    (void)in_sizes; (void)n_in; (void)out_size; (void)ws_size;
    const float* x    = (const float*)d_in[0];
    const float* eWih = (const float*)d_in[1];
    const float* eWhh = (const float*)d_in[2];
    const float* ebih = (const float*)d_in[3];
    const float* ebhh = (const float*)d_in[4];
    const float* dWih = (const float*)d_in[5];
    const float* dWhh = (const float*)d_in[6];
    const float* dbih = (const float*)d_in[7];
    const float* dbhh = (const float*)d_in[8];
    const float* regW = (const float*)d_in[9];
    const float* regb = (const float*)d_in[10];
    float* out = (float*)d_out;

    float* hbuf  = (float*)d_ws;                 // 2*512*256
    float* Mw    = hbuf + 2*Bsz*Hsz;             // 768*256
    float* gi0   = Mw + G3*Hsz;                  // 512*768
    float* cfold = gi0 + Bsz*G3;                 // 768 (+pad)
    int*   cnt   = (int*)(cfold + 1024);         // 16*512 ints

    hipMemsetAsync(hbuf, 0, (size_t)Bsz*Hsz*sizeof(float), stream); // h^0 = 0
    hipMemsetAsync(cnt, 0, (size_t)BG*CNT_STRIDE*sizeof(int), stream);

    // 768*256 + 768 + 512*768 = 590592 = 2307 * 256
    hipLaunchKernelGGL(gru_setup, dim3(2307), dim3(256), 0, stream,
                       x, dWih, dbih, regW, regb, Mw, cfold, gi0);

    hipFuncSetAttribute((const void*)gru_persistent,
                        hipFuncAttributeMaxDynamicSharedMemorySize, SMEM_BYTES);

    void* args[] = { (void*)&x, (void*)&eWih, (void*)&eWhh, (void*)&ebih, (void*)&ebhh,
                     (void*)&dWhh, (void*)&dbhh, (void*)&Mw, (void*)&cfold, (void*)&gi0,
                     (void*)&regW, (void*)&regb, (void*)&hbuf, (void*)&cnt, (void*)&out };
    hipError_t rc = hipLaunchCooperativeKernel((const void*)gru_persistent,
                                               dim3(NBLK), dim3(NTHR), args,
                                               SMEM_BYTES, stream);
    if (rc != hipSuccess) {
        // fallback: plain launch (256 blocks / 256 CUs at 1 block/CU co-reside)
        hipLaunchKernelGGL(gru_persistent, dim3(NBLK), dim3(NTHR), SMEM_BYTES, stream,
                           x, eWih, eWhh, ebih, ebhh, dWhh, dbhh, Mw, cfold, gi0,
                           regW, regb, hbuf, cnt, out);
    }
}

// Round 2
// 2780.525 us; speedup vs baseline: 3.8939x; 3.8939x over previous
//
#include <hip/hip_runtime.h>
#include <math.h>

#define Bsz 512
#define Fsz 64
#define Hsz 256
#define TSTEPS 128
#define G3 (3*Hsz)

#define BT 32            // batch rows per block
#define HT 16            // hidden cols per block
#define GB 48            // gate rows per block (3*HT)
#define HB 16            // hidden blocks
#define BG 16            // batch groups
#define NBLK (BG*HB)     // 256
#define NTHR 256
#define CNT_STRIDE 512

#define WPAD 260         // padded LDS row stride (K=256)
#define XPAD 68          // padded LDS row stride (K=64)

// LDS layout (floats)
#define OFF_WHH 0
#define OFF_AUX (GB*WPAD)            // decoder: M slice; encoder: wih + x tiles
#define OFF_H   (2*GB*WPAD)
#define OFF_RW  (OFF_H + BT*WPAD)
#define OFF_B1  (OFF_RW + 4*WPAD)
#define OFF_B2  (OFF_B1 + GB)
#define OFF_B3  (OFF_B2 + GB)
#define LDS_FLOATS (OFF_B3 + 8)
#define SMEM_BYTES (LDS_FLOATS*4)    // ~137.7 KB -> 1 block/CU

typedef float f32x4 __attribute__((ext_vector_type(4)));

__device__ __forceinline__ int grow(int lr, int hb) {
    return (lr >> 4)*Hsz + hb*HT + (lr & 15);   // gate*256 + hb*16 + j
}
__device__ __forceinline__ void fma4(float& a, f32x4 x, f32x4 y) {
    a += x.x*y.x; a += x.y*y.y; a += x.z*y.z; a += x.w*y.w;
}
__device__ __forceinline__ float sigmoidf_(float v) { return 1.0f/(1.0f + expf(-v)); }

// ---- cache-bypass (MALL-coherent) memory ops: sc0 sc1 = skip L1 and L2 ----
__device__ __forceinline__ f32x4 load_sys_b128(const float* p) {
    f32x4 r;
    asm volatile("global_load_dwordx4 %0, %1, off sc0 sc1"
                 : "=v"(r) : "v"(p) : "memory");
    return r;
}
__device__ __forceinline__ void store_sys_b32(float* p, float v) {
    asm volatile("global_store_dword %0, %1, off sc0 sc1"
                 :: "v"(p), "v"(v) : "memory");
}
__device__ __forceinline__ int load_sys_i32(const int* p) {
    int r;
    asm volatile("global_load_dword %0, %1, off sc0 sc1\n\ts_waitcnt vmcnt(0)"
                 : "=v"(r) : "v"(p) : "memory");
    return r;
}
__device__ __forceinline__ void waitcnt0() {
    asm volatile("s_waitcnt vmcnt(0)" ::: "memory");
}

// ---------------- setup: M = dec_Wih@reg_W, cfold = dec_Wih@reg_b + dec_bih,
// ---------------- gi0 = x[:,127,:]@dec_Wih.T + dec_bih
extern "C" __global__ void gru_setup(const float* __restrict__ x,
                                     const float* __restrict__ dWih,
                                     const float* __restrict__ dbih,
                                     const float* __restrict__ regW,
                                     const float* __restrict__ regb,
                                     float* __restrict__ Mw,
                                     float* __restrict__ cfold,
                                     float* __restrict__ gi0)
{
    int idx = blockIdx.x*blockDim.x + threadIdx.x;
    if (idx < G3*Hsz) {
        int g = idx >> 8, j = idx & 255;
        float a = 0.f;
        #pragma unroll 8
        for (int f = 0; f < Fsz; ++f) a += dWih[g*Fsz + f]*regW[f*Hsz + j];
        Mw[idx] = a;
    } else if (idx < G3*Hsz + G3) {
        int g = idx - G3*Hsz;
        float a = dbih[g];
        #pragma unroll 8
        for (int f = 0; f < Fsz; ++f) a += dWih[g*Fsz + f]*regb[f];
        cfold[g] = a;
    } else {
        int e = idx - (G3*Hsz + G3);
        if (e < Bsz*G3) {
            int b = e / G3, g = e - b*G3;
            const float* xp = x + (size_t)b*(256*64) + 127*64;
            float a = dbih[g];
            #pragma unroll 8
            for (int f = 0; f < Fsz; ++f) a += xp[f]*dWih[g*Fsz + f];
            gi0[e] = a;
        }
    }
}

// ---------------- persistent GRU kernel ----------------
extern "C" __global__ void __launch_bounds__(NTHR, 1)
gru_persistent(const float* __restrict__ x,
               const float* __restrict__ eWih, const float* __restrict__ eWhh,
               const float* __restrict__ ebih, const float* __restrict__ ebhh,
               const float* __restrict__ dWhh, const float* __restrict__ dbhh,
               const float* __restrict__ Mw,   const float* __restrict__ cfold,
               const float* __restrict__ gi0,  const float* __restrict__ regW,
               const float* __restrict__ regb,
               float* __restrict__ hbuf, int* __restrict__ cnt,
               float* __restrict__ out)
{
    extern __shared__ float lds[];
    const int tid = threadIdx.x;
    const int blk = blockIdx.x;
    const int bg  = blk >> 4;
    const int hb  = blk & 15;
    const int tg  = tid & 15;          // hidden col within slice
    const int ks  = (tid >> 4) & 1;    // k-split half
    const int tb  = tid >> 5;          // batch quad 0..7
    const int hcol = hb*HT + tg;
    const int lb  = ks*2;              // local epilogue rows lb, lb+1

    float* s_whh = lds + OFF_WHH;   // [48][260]
    float* s_aux = lds + OFF_AUX;   // decoder: M [48][260]
    float* s_wih = s_aux;           // encoder: [48][68]
    float* s_x   = s_aux + GB*XPAD; // encoder: [32][68]
    float* s_h   = lds + OFF_H;     // [32][260]
    float* s_rw  = lds + OFF_RW;    // [4][260]
    float* s_b1  = lds + OFF_B1;    // 48: bih (enc) / cfold (dec)
    float* s_b2  = lds + OFF_B2;    // 48: bhh
    float* s_b3  = lds + OFF_B3;    // 4: reg_b slice

    int* mycnt = cnt + bg*CNT_STRIDE;

    // ---- stage encoder weights (once, cached loads: read-only data) ----
    for (int idx = tid; idx < GB*64; idx += NTHR) {
        int lr = idx >> 6, c4 = idx & 63;
        *(f32x4*)(s_whh + lr*WPAD + c4*4) =
            *(const f32x4*)(eWhh + (size_t)grow(lr,hb)*Hsz + c4*4);
    }
    for (int idx = tid; idx < GB*16; idx += NTHR) {
        int lr = idx >> 4, c4 = idx & 15;
        *(f32x4*)(s_wih + lr*XPAD + c4*4) =
            *(const f32x4*)(eWih + (size_t)grow(lr,hb)*Fsz + c4*4);
    }
    if (tid < GB) { int g = grow(tid,hb); s_b1[tid] = ebih[g]; s_b2[tid] = ebhh[g]; }
    __syncthreads();

    int parity = 0;

    // =================== ENCODER ===================
    for (int s = 0; s < TSTEPS; ++s) {
        // ---- stage x tile + x-GEMM (independent of h: before the wait) ----
        for (int idx = tid; idx < BT*16; idx += NTHR) {
            int r = idx >> 4, c4 = idx & 15;
            *(f32x4*)(s_x + r*XPAD + c4*4) =
                *(const f32x4*)(x + (size_t)(bg*BT + r)*(256*64) + s*Fsz + c4*4);
        }
        __syncthreads();

        float iR[4] = {0,0,0,0}, iZ[4] = {0,0,0,0}, iN[4] = {0,0,0,0};
        {
            const f32x4* u0p = (const f32x4*)(s_wih + tg*XPAD) + ks*8;
            const f32x4* u1p = (const f32x4*)(s_wih + (tg+16)*XPAD) + ks*8;
            const f32x4* u2p = (const f32x4*)(s_wih + (tg+32)*XPAD) + ks*8;
            const f32x4* xp0 = (const f32x4*)(s_x + (tb*4+0)*XPAD) + ks*8;
            const f32x4* xp1 = (const f32x4*)(s_x + (tb*4+1)*XPAD) + ks*8;
            const f32x4* xp2 = (const f32x4*)(s_x + (tb*4+2)*XPAD) + ks*8;
            const f32x4* xp3 = (const f32x4*)(s_x + (tb*4+3)*XPAD) + ks*8;
            #pragma unroll
            for (int k = 0; k < 8; ++k) {
                f32x4 u0 = u0p[k], u1 = u1p[k], u2 = u2p[k];
                f32x4 x0 = xp0[k], x1 = xp1[k], x2 = xp2[k], x3 = xp3[k];
                fma4(iR[0],x0,u0); fma4(iZ[0],x0,u1); fma4(iN[0],x0,u2);
                fma4(iR[1],x1,u0); fma4(iZ[1],x1,u1); fma4(iN[1],x1,u2);
                fma4(iR[2],x2,u0); fma4(iZ[2],x2,u1); fma4(iN[2],x2,u2);
                fma4(iR[3],x3,u0); fma4(iZ[3],x3,u1); fma4(iN[3],x3,u2);
            }
        }

        // ---- wait for producers (relaxed MALL polling, no cache flushes) ----
        if (s > 0) {
            if (tid == 0) {
                while (load_sys_i32(mycnt + s) < HB) __builtin_amdgcn_s_sleep(2);
            }
            __syncthreads();
        }

        // ---- stage h via MALL (cache-bypass) ----
        const float* hin = hbuf + (size_t)parity*Bsz*Hsz;
        {
            f32x4 t[8];
            #pragma unroll
            for (int j = 0; j < 8; ++j) {
                int idx = tid + j*NTHR;
                int r = idx >> 6, c4 = idx & 63;
                t[j] = load_sys_b128(hin + (size_t)(bg*BT + r)*Hsz + c4*4);
            }
            waitcnt0();
            #pragma unroll
            for (int j = 0; j < 8; ++j) {
                int idx = tid + j*NTHR;
                int r = idx >> 6, c4 = idx & 63;
                *(f32x4*)(s_h + r*WPAD + c4*4) = t[j];
            }
        }
        __syncthreads();

        // ---- h-GEMM: 4 batch rows x 3 gates, k-split by ks ----
        float hR[4] = {0,0,0,0}, hZ[4] = {0,0,0,0}, hN[4] = {0,0,0,0};
        {
            const f32x4* w0p = (const f32x4*)(s_whh + tg*WPAD) + ks*32;
            const f32x4* w1p = (const f32x4*)(s_whh + (tg+16)*WPAD) + ks*32;
            const f32x4* w2p = (const f32x4*)(s_whh + (tg+32)*WPAD) + ks*32;
            const f32x4* h0p = (const f32x4*)(s_h + (tb*4+0)*WPAD) + ks*32;
            const f32x4* h1p = (const f32x4*)(s_h + (tb*4+1)*WPAD) + ks*32;
            const f32x4* h2p = (const f32x4*)(s_h + (tb*4+2)*WPAD) + ks*32;
            const f32x4* h3p = (const f32x4*)(s_h + (tb*4+3)*WPAD) + ks*32;
            #pragma unroll 4
            for (int k = 0; k < 32; ++k) {
                f32x4 w0 = w0p[k], w1 = w1p[k], w2 = w2p[k];
                f32x4 h0 = h0p[k], h1 = h1p[k], h2 = h2p[k], h3 = h3p[k];
                fma4(hR[0],h0,w0); fma4(hZ[0],h0,w1); fma4(hN[0],h0,w2);
                fma4(hR[1],h1,w0); fma4(hZ[1],h1,w1); fma4(hN[1],h1,w2);
                fma4(hR[2],h2,w0); fma4(hZ[2],h2,w1); fma4(hN[2],h2,w2);
                fma4(hR[3],h3,w0); fma4(hZ[3],h3,w1); fma4(hN[3],h3,w2);
            }
        }

        // ---- combine + cross-ks reduce (partner = lane^16, same wave) ----
        float cR[4], cZ[4];
        #pragma unroll
        for (int b = 0; b < 4; ++b) { cR[b] = hR[b] + iR[b]; cZ[b] = hZ[b] + iZ[b]; }
        #pragma unroll
        for (int b = 0; b < 4; ++b) {
            cR[b] += __shfl_xor(cR[b], 16);
            cZ[b] += __shfl_xor(cZ[b], 16);
            hN[b] += __shfl_xor(hN[b], 16);
            iN[b] += __shfl_xor(iN[b], 16);
        }

        // ---- epilogue: 2 rows per thread ----
        float* hout = hbuf + (size_t)(parity^1)*Bsz*Hsz;
        {
            float biR = s_b1[tg], biZ = s_b1[tg+16], biN = s_b1[tg+32];
            float bhR = s_b2[tg], bhZ = s_b2[tg+16], bhN = s_b2[tg+32];
            #pragma unroll
            for (int e = 0; e < 2; ++e) {
                int b = lb + e;
                int row = tb*4 + b;
                float r = sigmoidf_(cR[b] + biR + bhR);
                float z = sigmoidf_(cZ[b] + biZ + bhZ);
                float n = tanhf(iN[b] + biN + r*(hN[b] + bhN));
                float ho = s_h[row*WPAD + hcol];
                float hv = (1.0f - z)*n + z*ho;
                store_sys_b32(hout + (size_t)(bg*BT + row)*Hsz + hcol, hv);
            }
        }
        waitcnt0();
        __syncthreads();
        if (tid == 0)
            __hip_atomic_fetch_add(mycnt + s + 1, 1, __ATOMIC_RELAXED,
                                   __HIP_MEMORY_SCOPE_SYSTEM);
        parity ^= 1;
    }

    // ---- stage decoder weights ----
    for (int idx = tid; idx < GB*64; idx += NTHR) {
        int lr = idx >> 6, c4 = idx & 63;
        *(f32x4*)(s_whh + lr*WPAD + c4*4) =
            *(const f32x4*)(dWhh + (size_t)grow(lr,hb)*Hsz + c4*4);
        *(f32x4*)(s_aux + lr*WPAD + c4*4) =
            *(const f32x4*)(Mw + (size_t)grow(lr,hb)*Hsz + c4*4);
    }
    {
        int r = tid >> 6, c4 = tid & 63;
        *(f32x4*)(s_rw + r*WPAD + c4*4) =
            *(const f32x4*)(regW + (size_t)(hb*4 + r)*Hsz + c4*4);
    }
    if (tid < GB) { int g = grow(tid,hb); s_b1[tid] = cfold[g]; s_b2[tid] = dbhh[g]; }
    if (tid < 4) s_b3[tid] = regb[hb*4 + tid];
    __syncthreads();

    // =================== DECODER ===================
    for (int i = 0; i < TSTEPS; ++i) {
        const int s = TSTEPS + i;
        if (tid == 0) {
            while (load_sys_i32(mycnt + s) < HB) __builtin_amdgcn_s_sleep(2);
        }
        __syncthreads();

        const float* hin = hbuf + (size_t)parity*Bsz*Hsz;
        {
            f32x4 t[8];
            #pragma unroll
            for (int j = 0; j < 8; ++j) {
                int idx = tid + j*NTHR;
                int r = idx >> 6, c4 = idx & 63;
                t[j] = load_sys_b128(hin + (size_t)(bg*BT + r)*Hsz + c4*4);
            }
            waitcnt0();
            #pragma unroll
            for (int j = 0; j < 8; ++j) {
                int idx = tid + j*NTHR;
                int r = idx >> 6, c4 = idx & 63;
                *(f32x4*)(s_h + r*WPAD + c4*4) = t[j];
            }
        }
        __syncthreads();

        float hR[4] = {0,0,0,0}, hZ[4] = {0,0,0,0}, hN[4] = {0,0,0,0};
        float iR[4] = {0,0,0,0}, iZ[4] = {0,0,0,0}, iN[4] = {0,0,0,0};
        {
            const f32x4* w0p = (const f32x4*)(s_whh + tg*WPAD) + ks*32;
            const f32x4* w1p = (const f32x4*)(s_whh + (tg+16)*WPAD) + ks*32;
            const f32x4* w2p = (const f32x4*)(s_whh + (tg+32)*WPAD) + ks*32;
            const f32x4* h0p = (const f32x4*)(s_h + (tb*4+0)*WPAD) + ks*32;
            const f32x4* h1p = (const f32x4*)(s_h + (tb*4+1)*WPAD) + ks*32;
            const f32x4* h2p = (const f32x4*)(s_h + (tb*4+2)*WPAD) + ks*32;
            const f32x4* h3p = (const f32x4*)(s_h + (tb*4+3)*WPAD) + ks*32;
            if (i == 0) {
                #pragma unroll 4
                for (int k = 0; k < 32; ++k) {
                    f32x4 w0 = w0p[k], w1 = w1p[k], w2 = w2p[k];
                    f32x4 h0 = h0p[k], h1 = h1p[k], h2 = h2p[k], h3 = h3p[k];
                    fma4(hR[0],h0,w0); fma4(hZ[0],h0,w1); fma4(hN[0],h0,w2);
                    fma4(hR[1],h1,w0); fma4(hZ[1],h1,w1); fma4(hN[1],h1,w2);
                    fma4(hR[2],h2,w0); fma4(hZ[2],h2,w1); fma4(hN[2],h2,w2);
                    fma4(hR[3],h3,w0); fma4(hZ[3],h3,w1); fma4(hN[3],h3,w2);
                }
            } else {
                const f32x4* m0p = (const f32x4*)(s_aux + tg*WPAD) + ks*32;
                const f32x4* m1p = (const f32x4*)(s_aux + (tg+16)*WPAD) + ks*32;
                const f32x4* m2p = (const f32x4*)(s_aux + (tg+32)*WPAD) + ks*32;
                #pragma unroll 2
                for (int k = 0; k < 32; ++k) {
                    f32x4 w0 = w0p[k], w1 = w1p[k], w2 = w2p[k];
                    f32x4 m0 = m0p[k], m1 = m1p[k], m2 = m2p[k];
                    f32x4 h0 = h0p[k], h1 = h1p[k], h2 = h2p[k], h3 = h3p[k];
                    fma4(hR[0],h0,w0); fma4(hZ[0],h0,w1); fma4(hN[0],h0,w2);
                    fma4(hR[1],h1,w0); fma4(hZ[1],h1,w1); fma4(hN[1],h1,w2);
                    fma4(hR[2],h2,w0); fma4(hZ[2],h2,w1); fma4(hN[2],h2,w2);
                    fma4(hR[3],h3,w0); fma4(hZ[3],h3,w1); fma4(hN[3],h3,w2);
                    fma4(iR[0],h0,m0); fma4(iZ[0],h0,m1); fma4(iN[0],h0,m2);
                    fma4(iR[1],h1,m0); fma4(iZ[1],h1,m1); fma4(iN[1],h1,m2);
                    fma4(iR[2],h2,m0); fma4(iZ[2],h2,m1); fma4(iN[2],h2,m2);
                    fma4(iR[3],h3,m0); fma4(iZ[3],h3,m1); fma4(iN[3],h3,m2);
                }
            }
        }

        float cR[4], cZ[4];
        #pragma unroll
        for (int b = 0; b < 4; ++b) { cR[b] = hR[b] + iR[b]; cZ[b] = hZ[b] + iZ[b]; }
        #pragma unroll
        for (int b = 0; b < 4; ++b) {
            cR[b] += __shfl_xor(cR[b], 16);
            cZ[b] += __shfl_xor(cZ[b], 16);
            hN[b] += __shfl_xor(hN[b], 16);
            iN[b] += __shfl_xor(iN[b], 16);
        }

        float* hout = hbuf + (size_t)(parity^1)*Bsz*Hsz;
        {
            float bhR = s_b2[tg], bhZ = s_b2[tg+16], bhN = s_b2[tg+32];
            #pragma unroll
            for (int e = 0; e < 2; ++e) {
                int b = lb + e;
                int row = tb*4 + b;
                float r, z, n;
                if (i == 0) {
                    const float* gp = gi0 + (size_t)(bg*BT + row)*G3;
                    float giR = gp[hcol], giZ = gp[256+hcol], giN = gp[512+hcol];
                    r = sigmoidf_(cR[b] + giR + bhR);
                    z = sigmoidf_(cZ[b] + giZ + bhZ);
                    n = tanhf(giN + r*(hN[b] + bhN));
                } else {
                    float biR = s_b1[tg], biZ = s_b1[tg+16], biN = s_b1[tg+32];
                    r = sigmoidf_(cR[b] + biR + bhR);
                    z = sigmoidf_(cZ[b] + biZ + bhZ);
                    n = tanhf(iN[b] + biN + r*(hN[b] + bhN));
                }
                float ho = s_h[row*WPAD + hcol];
                float hv = (1.0f - z)*n + z*ho;
                store_sys_b32(hout + (size_t)(bg*BT + row)*Hsz + hcol, hv);
            }
        }
        waitcnt0();
        __syncthreads();
        if (tid == 0)
            __hip_atomic_fetch_add(mycnt + s + 1, 1, __ATOMIC_RELAXED,
                                   __HIP_MEMORY_SCOPE_SYSTEM);

        // ---- out_{i-1} (off the critical path: after the flag post) ----
        if (i >= 1 && tid < 128) {
            int bl = tid >> 2, fl = tid & 3;
            const f32x4* hp = (const f32x4*)(s_h + bl*WPAD);
            const f32x4* wp = (const f32x4*)(s_rw + fl*WPAD);
            float acc = s_b3[fl];
            #pragma unroll 8
            for (int k = 0; k < 64; ++k) fma4(acc, hp[k], wp[k]);
            out[(size_t)(bg*BT + bl)*(TSTEPS*Fsz) + (size_t)(i-1)*Fsz + hb*4 + fl] = acc;
        }
        parity ^= 1;
    }

    // ---- final out_{127} from h^d_128 ----
    {
        const int s = 2*TSTEPS;
        if (tid == 0) {
            while (load_sys_i32(mycnt + s) < HB) __builtin_amdgcn_s_sleep(2);
        }
        __syncthreads();
        const float* hin = hbuf + (size_t)parity*Bsz*Hsz;
        {
            f32x4 t[8];
            #pragma unroll
            for (int j = 0; j < 8; ++j) {
                int idx = tid + j*NTHR;
                int r = idx >> 6, c4 = idx & 63;
                t[j] = load_sys_b128(hin + (size_t)(bg*BT + r)*Hsz + c4*4);
            }
            waitcnt0();
            #pragma unroll
            for (int j = 0; j < 8; ++j) {
                int idx = tid + j*NTHR;
                int r = idx >> 6, c4 = idx & 63;
                *(f32x4*)(s_h + r*WPAD + c4*4) = t[j];
            }
        }
        __syncthreads();
        if (tid < 128) {
            int bl = tid >> 2, fl = tid & 3;
            const f32x4* hp = (const f32x4*)(s_h + bl*WPAD);
            const f32x4* wp = (const f32x4*)(s_rw + fl*WPAD);
            float acc = s_b3[fl];
            #pragma unroll 8
            for (int k = 0; k < 64; ++k) fma4(acc, hp[k], wp[k]);
            out[(size_t)(bg*BT + bl)*(TSTEPS*Fsz) + (size_t)(TSTEPS-1)*Fsz + hb*4 + fl] = acc;
        }
    }
}

extern "C" void kernel_launch(void* const* d_in, const int* in_sizes, int n_in,
                              void* d_out, int out_size, void* d_ws, size_t ws_size,
                              hipStream_t stream)
{
    (void)in_sizes; (void)n_in; (void)out_size; (void)ws_size;
    const float* x    = (const float*)d_in[0];
    const float* eWih = (const float*)d_in[1];
    const float* eWhh = (const float*)d_in[2];
    const float* ebih = (const float*)d_in[3];
    const float* ebhh = (const float*)d_in[4];
    const float* dWih = (const float*)d_in[5];
    const float* dWhh = (const float*)d_in[6];
    const float* dbih = (const float*)d_in[7];
    const float* dbhh = (const float*)d_in[8];
    const float* regW = (const float*)d_in[9];
    const float* regb = (const float*)d_in[10];
    float* out = (float*)d_out;

    float* hbuf  = (float*)d_ws;                 // 2*512*256
    float* Mw    = hbuf + 2*Bsz*Hsz;             // 768*256
    float* gi0   = Mw + G3*Hsz;                  // 512*768
    float* cfold = gi0 + Bsz*G3;                 // 768 (+pad)
    int*   cnt   = (int*)(cfold + 1024);         // 16*512 ints

    hipMemsetAsync(hbuf, 0, (size_t)Bsz*Hsz*sizeof(float), stream); // h^0 = 0
    hipMemsetAsync(cnt, 0, (size_t)BG*CNT_STRIDE*sizeof(int), stream);

    hipLaunchKernelGGL(gru_setup, dim3(2307), dim3(256), 0, stream,
                       x, dWih, dbih, regW, regb, Mw, cfold, gi0);

    hipFuncSetAttribute((const void*)gru_persistent,
                        hipFuncAttributeMaxDynamicSharedMemorySize, SMEM_BYTES);

    void* args[] = { (void*)&x, (void*)&eWih, (void*)&eWhh, (void*)&ebih, (void*)&ebhh,
                     (void*)&dWhh, (void*)&dbhh, (void*)&Mw, (void*)&cfold, (void*)&gi0,
                     (void*)&regW, (void*)&regb, (void*)&hbuf, (void*)&cnt, (void*)&out };
    hipError_t rc = hipLaunchCooperativeKernel((const void*)gru_persistent,
                                               dim3(NBLK), dim3(NTHR), args,
                                               SMEM_BYTES, stream);
    if (rc != hipSuccess) {
        hipLaunchKernelGGL(gru_persistent, dim3(NBLK), dim3(NTHR), SMEM_BYTES, stream,
                           x, eWih, eWhh, ebih, ebhh, dWhh, dbhh, Mw, cfold, gi0,
                           regW, regb, hbuf, cnt, out);
    }
}

// Round 4
// 1185.198 us; speedup vs baseline: 9.1352x; 2.3460x over previous
//
#include <hip/hip_runtime.h>
#include <math.h>

#define Bsz 512
#define Fsz 64
#define Hsz 256
#define TSTEPS 128
#define G3 768

#define BG 16            // batch groups (32 rows each)
#define HB 16            // hidden-slice blocks (16 cols x 3 gates each)
#define NBLK 256
#define NTHR 256
#define CNT_STRIDE 512
#define POLLER 192       // wave-3 lane 0 does the flag polling

#define AP 264           // bf16 row stride for h tiles (256+8)
#define XAP 72           // bf16 row stride for x tiles (64+8)

// LDS layout (bytes)
#define OFF_AH  0                      // u16 [32][AP]  h hi
#define OFF_AL  16896                  // u16 [32][AP]  h lo
#define OFF_XH  33792                  // u16 [32][XAP] x hi
#define OFF_XL  38400                  // u16 [32][XAP] x lo
#define OFF_RED 43008                  // f32x4 [4 waves][8 slots][64 lanes]
#define OFF_B   75776                  // 128 floats of biases
#define SMEM_BYTES (OFF_B + 512)       // ~76.3 KB -> 1 block/CU

typedef float f32x4 __attribute__((ext_vector_type(4)));
typedef short s16x8 __attribute__((ext_vector_type(8)));
typedef unsigned short u16x4 __attribute__((ext_vector_type(4)));
typedef unsigned int  u32x4 __attribute__((ext_vector_type(4)));

#define MF(a,b,c) __builtin_amdgcn_mfma_f32_16x16x32_bf16(a,b,c,0,0,0)

static __device__ __forceinline__ unsigned short bf16_rne(float f){
    union { float f; unsigned u; } v; v.f = f;
    return (unsigned short)((v.u + 0x7FFFu + ((v.u >> 16) & 1u)) >> 16);
}
static __device__ __forceinline__ float bf16_to_f(unsigned short h){
    union { unsigned u; float f; } v; v.u = ((unsigned)h) << 16; return v.f;
}
// split 8 consecutive fp32 into hi/lo bf16 fragments
static __device__ __forceinline__ void split8(const float* p, s16x8& hi, s16x8& lo){
    #pragma unroll
    for (int t = 0; t < 8; ++t){
        float f = p[t];
        unsigned short h = bf16_rne(f);
        hi[t] = (short)h;
        lo[t] = (short)bf16_rne(f - bf16_to_f(h));
    }
}
static __device__ __forceinline__ float sigmoidf_(float v){ return 1.0f/(1.0f + expf(-v)); }

// ---- MALL-coherent (cache-bypass) ops: sc0 sc1 = skip L1+L2 ----
__device__ __forceinline__ u32x4 load_sys_b128u(const unsigned* p){
    u32x4 r;
    asm volatile("global_load_dwordx4 %0, %1, off sc0 sc1" : "=v"(r) : "v"(p) : "memory");
    return r;
}
__device__ __forceinline__ void store_sys_b32u(unsigned* p, unsigned v){
    asm volatile("global_store_dword %0, %1, off sc0 sc1" :: "v"(p), "v"(v) : "memory");
}
__device__ __forceinline__ int load_sys_i32(const int* p){
    int r;
    asm volatile("global_load_dword %0, %1, off sc0 sc1\n\ts_waitcnt vmcnt(0)"
                 : "=v"(r) : "v"(p) : "memory");
    return r;
}
__device__ __forceinline__ void waitcnt0(){ asm volatile("s_waitcnt vmcnt(0)" ::: "memory"); }
// Zero-instruction register barrier: forces every use of v to be scheduled
// after this point (and thus after a preceding volatile s_waitcnt). Without
// it, pure-ALU unpack of asm-load results can be hoisted above the waitcnt
// (the NaN bug in R3).
__device__ __forceinline__ void regbar(u32x4& v){ asm volatile("" : "+v"(v)); }

// ---------------- setup: M = dec_Wih@reg_W, cfold = dec_Wih@reg_b + dec_bih,
// ---------------- gi0 = x[:,127,:]@dec_Wih.T + dec_bih
extern "C" __global__ void gru_setup(const float* __restrict__ x,
                                     const float* __restrict__ dWih,
                                     const float* __restrict__ dbih,
                                     const float* __restrict__ regW,
                                     const float* __restrict__ regb,
                                     float* __restrict__ Mw,
                                     float* __restrict__ cfold,
                                     float* __restrict__ gi0)
{
    int idx = blockIdx.x*blockDim.x + threadIdx.x;
    if (idx < G3*Hsz) {
        int g = idx >> 8, j = idx & 255;
        float a = 0.f;
        #pragma unroll 8
        for (int f = 0; f < Fsz; ++f) a += dWih[g*Fsz + f]*regW[f*Hsz + j];
        Mw[idx] = a;
    } else if (idx < G3*Hsz + G3) {
        int g = idx - G3*Hsz;
        float a = dbih[g];
        #pragma unroll 8
        for (int f = 0; f < Fsz; ++f) a += dWih[g*Fsz + f]*regb[f];
        cfold[g] = a;
    } else {
        int e = idx - (G3*Hsz + G3);
        if (e < Bsz*G3) {
            int b = e / G3, g = e - b*G3;
            const float* xp = x + (size_t)b*(256*64) + 127*64;
            float a = dbih[g];
            #pragma unroll 8
            for (int f = 0; f < Fsz; ++f) a += xp[f]*dWih[g*Fsz + f];
            gi0[e] = a;
        }
    }
}

// ---------------- persistent GRU kernel (MFMA split-bf16) ----------------
extern "C" __global__ void __launch_bounds__(NTHR, 1)
gru_persistent(const float* __restrict__ x,
               const float* __restrict__ eWih, const float* __restrict__ eWhh,
               const float* __restrict__ ebih, const float* __restrict__ ebhh,
               const float* __restrict__ dWhh, const float* __restrict__ dbhh,
               const float* __restrict__ Mw,   const float* __restrict__ cfold,
               const float* __restrict__ gi0,  const float* __restrict__ regW,
               const float* __restrict__ regb,
               unsigned* __restrict__ hbuf, int* __restrict__ cnt,
               float* __restrict__ out)
{
    extern __shared__ char lds[];
    unsigned short* s_ah = (unsigned short*)(lds + OFF_AH);
    unsigned short* s_al = (unsigned short*)(lds + OFF_AL);
    unsigned short* s_xh = (unsigned short*)(lds + OFF_XH);
    unsigned short* s_xl = (unsigned short*)(lds + OFF_XL);
    float* s_red  = (float*)(lds + OFF_RED);
    float* s_bias = (float*)(lds + OFF_B);    // enc: [0..63]; dec: bc [0..47]
    float* s_dbh  = s_bias + 64;              // dec: dbhh slices [0..47]
    float* s_b3   = s_bias + 112;             // reg_b slice [0..3]

    const int tid  = threadIdx.x;
    const int wv   = tid >> 6;        // wave 0..3 (K-split-4 over K=256)
    const int lane = tid & 63;
    const int quad = lane >> 4;
    const int lcol = lane & 15;
    const int bg   = blockIdx.x >> 4;
    const int hb   = blockIdx.x & 15;
    const int hcol = hb*16 + lcol;    // this lane's hidden column
    int* mycnt = cnt + bg*CNT_STRIDE;
    const f32x4 z4 = {0.f, 0.f, 0.f, 0.f};

    // ---- encoder weight fragments (B-operand: n=lcol -> row j of W, k contiguous) ----
    s16x8 wfh[3][2], wfl[3][2];   // Whh: [gate][q]; this wave's k = wv*64 + q*32 + quad*8
    s16x8 ufh[3], ufl[3];         // Wih: waves 0,1 only; k = wv*32 + quad*8
    #pragma unroll
    for (int g = 0; g < 3; ++g)
        #pragma unroll
        for (int q = 0; q < 2; ++q)
            split8(eWhh + (size_t)(g*256 + hcol)*256 + wv*64 + q*32 + quad*8,
                   wfh[g][q], wfl[g][q]);
    if (wv < 2){
        #pragma unroll
        for (int g = 0; g < 3; ++g)
            split8(eWih + (size_t)(g*256 + hcol)*64 + wv*32 + quad*8, ufh[g], ufl[g]);
    }
    if (tid < 16){
        int c = hb*16 + tid;
        s_bias[tid]    = ebih[c]       + ebhh[c];
        s_bias[16+tid] = ebih[256+c]   + ebhh[256+c];
        s_bias[32+tid] = ebih[512+c];
        s_bias[48+tid] = ebhh[512+c];
    }
    __syncthreads();

    int parity = 0;

    // =================== ENCODER ===================
    for (int s = 0; s < TSTEPS; ++s) {
        // acc init (wave 0 carries biases; others zero -> summed in reduce)
        f32x4 aR[2], aZ[2], aNi[2], aNh[2];
        if (wv == 0){
            float bR = s_bias[lcol], bZ = s_bias[16+lcol];
            float bNi = s_bias[32+lcol], bNh = s_bias[48+lcol];
            #pragma unroll
            for (int m = 0; m < 2; ++m){
                aR[m] = (f32x4){bR,bR,bR,bR}; aZ[m] = (f32x4){bZ,bZ,bZ,bZ};
                aNi[m] = (f32x4){bNi,bNi,bNi,bNi}; aNh[m] = (f32x4){bNh,bNh,bNh,bNh};
            }
        } else {
            #pragma unroll
            for (int m = 0; m < 2; ++m){ aR[m]=z4; aZ[m]=z4; aNi[m]=z4; aNh[m]=z4; }
        }

        // ---- stage x tile (all waves), independent of h; normal cached loads ----
        #pragma unroll
        for (int jj = 0; jj < 2; ++jj){
            int flat = (wv*2 + jj)*64 + lane;      // 0..511 = 32 rows x 16 float4
            int row = flat >> 4, c4 = flat & 15;
            f32x4 xv = *(const f32x4*)(x + (size_t)(bg*32+row)*(256*64) + (size_t)s*64 + c4*4);
            u16x4 xh, xl;
            #pragma unroll
            for (int t = 0; t < 4; ++t){
                unsigned short h = bf16_rne(xv[t]);
                xh[t] = h; xl[t] = bf16_rne(xv[t] - bf16_to_f(h));
            }
            *(u16x4*)(s_xh + row*XAP + c4*4) = xh;
            *(u16x4*)(s_xl + row*XAP + c4*4) = xl;
        }
        __syncthreads();   // Bx: x staged

        // ---- x-MFMA (waves 0,1 split K=64) ----
        if (wv < 2){
            #pragma unroll
            for (int m = 0; m < 2; ++m){
                const int ko = wv*32 + quad*8;
                s16x8 xah = *(const s16x8*)(s_xh + (m*16+lcol)*XAP + ko);
                s16x8 xal = *(const s16x8*)(s_xl + (m*16+lcol)*XAP + ko);
                aR[m]=MF(xah,ufh[0],aR[m]); aR[m]=MF(xah,ufl[0],aR[m]); aR[m]=MF(xal,ufh[0],aR[m]);
                aZ[m]=MF(xah,ufh[1],aZ[m]); aZ[m]=MF(xah,ufl[1],aZ[m]); aZ[m]=MF(xal,ufh[1],aZ[m]);
                aNi[m]=MF(xah,ufh[2],aNi[m]); aNi[m]=MF(xah,ufl[2],aNi[m]); aNi[m]=MF(xal,ufh[2],aNi[m]);
            }
        }

        // ---- wait for producers ----
        if (s > 0 && tid == POLLER){
            while (load_sys_i32(mycnt + s) < HB) __builtin_amdgcn_s_sleep(2);
        }
        __syncthreads();   // B1

        // ---- load packed h via MALL, unpack to hi/lo LDS (all waves) ----
        const unsigned* hin = hbuf + (size_t)parity*Bsz*Hsz;
        {
            u32x4 t[8];
            #pragma unroll
            for (int jj = 0; jj < 8; ++jj){
                int flat = (wv*8 + jj)*64 + lane;  // 0..2047 = 32 rows x 64 u32x4
                int row = flat >> 6, c4 = flat & 63;
                t[jj] = load_sys_b128u(hin + (size_t)(bg*32+row)*256 + c4*4);
            }
            waitcnt0();
            #pragma unroll
            for (int jj = 0; jj < 8; ++jj) regbar(t[jj]);   // pin unpack after waitcnt
            #pragma unroll
            for (int jj = 0; jj < 8; ++jj){
                int flat = (wv*8 + jj)*64 + lane;
                int row = flat >> 6, c4 = flat & 63;
                u16x4 hh, ll;
                #pragma unroll
                for (int e = 0; e < 4; ++e){
                    unsigned u = t[jj][e];
                    hh[e] = (unsigned short)(u >> 16);
                    ll[e] = (unsigned short)(u & 0xFFFFu);
                }
                *(u16x4*)(s_ah + row*AP + c4*4) = hh;
                *(u16x4*)(s_al + row*AP + c4*4) = ll;
            }
        }
        __syncthreads();   // B2

        // ---- h-MFMA: this wave's K range = [wv*64, wv*64+64) ----
        #pragma unroll
        for (int m = 0; m < 2; ++m){
            #pragma unroll
            for (int q = 0; q < 2; ++q){
                const int ko = wv*64 + q*32 + quad*8;
                s16x8 ah = *(const s16x8*)(s_ah + (m*16+lcol)*AP + ko);
                s16x8 al = *(const s16x8*)(s_al + (m*16+lcol)*AP + ko);
                aR[m]=MF(ah,wfh[0][q],aR[m]); aR[m]=MF(ah,wfl[0][q],aR[m]); aR[m]=MF(al,wfh[0][q],aR[m]);
                aZ[m]=MF(ah,wfh[1][q],aZ[m]); aZ[m]=MF(ah,wfl[1][q],aZ[m]); aZ[m]=MF(al,wfh[1][q],aZ[m]);
                aNh[m]=MF(ah,wfh[2][q],aNh[m]); aNh[m]=MF(ah,wfl[2][q],aNh[m]); aNh[m]=MF(al,wfh[2][q],aNh[m]);
            }
        }

        // ---- K-reduction across waves via LDS ----
        #pragma unroll
        for (int m = 0; m < 2; ++m){
            f32x4* rp = (f32x4*)s_red + (wv*8 + m*4)*64 + lane;
            rp[0] = aR[m]; rp[64] = aZ[m]; rp[128] = aNi[m]; rp[192] = aNh[m];
        }
        __syncthreads();   // B3

        unsigned* hout = hbuf + (size_t)(parity^1)*Bsz*Hsz;
        if (wv < 2){
            const int m = wv;
            f32x4 R = z4, Z = z4, Ni = z4, Nh = z4;
            #pragma unroll
            for (int w = 0; w < 4; ++w){
                const f32x4* rp = (const f32x4*)s_red + (w*8 + m*4)*64 + lane;
                R += rp[0]; Z += rp[64]; Ni += rp[128]; Nh += rp[192];
            }
            #pragma unroll
            for (int j = 0; j < 4; ++j){
                int rl = m*16 + quad*4 + j;
                float r = sigmoidf_(R[j]);
                float z = sigmoidf_(Z[j]);
                float n = tanhf(Ni[j] + r*Nh[j]);
                float hold = bf16_to_f(s_ah[rl*AP + hcol]) + bf16_to_f(s_al[rl*AP + hcol]);
                float hv = (1.0f - z)*n + z*hold;
                unsigned short p1 = bf16_rne(hv);
                unsigned short p0 = bf16_rne(hv - bf16_to_f(p1));
                store_sys_b32u(hout + (size_t)(bg*32+rl)*256 + hcol,
                               (((unsigned)p1) << 16) | (unsigned)p0);
            }
            waitcnt0();
        }
        __syncthreads();   // B4
        if (tid == POLLER)
            __hip_atomic_fetch_add(mycnt + s + 1, 1, __ATOMIC_RELAXED,
                                   __HIP_MEMORY_SCOPE_SYSTEM);
        parity ^= 1;
    }

    // ---- decoder weight fragments ----
    s16x8 mfh[3][2], mfl[3][2];   // M = dec_Wih@reg_W
    #pragma unroll
    for (int g = 0; g < 3; ++g)
        #pragma unroll
        for (int q = 0; q < 2; ++q){
            split8(dWhh + (size_t)(g*256 + hcol)*256 + wv*64 + q*32 + quad*8,
                   wfh[g][q], wfl[g][q]);
            split8(Mw   + (size_t)(g*256 + hcol)*256 + wv*64 + q*32 + quad*8,
                   mfh[g][q], mfl[g][q]);
        }
    s16x8 rwh[8], rwl[8];         // regW rows hb*4+(lcol&3), waves 2,3 (out-GEMM)
    if (wv >= 2){
        #pragma unroll
        for (int q8 = 0; q8 < 8; ++q8)
            split8(regW + (size_t)(hb*4 + (lcol & 3))*256 + q8*32 + quad*8,
                   rwh[q8], rwl[q8]);
    }
    if (tid < 16){
        int c = hb*16 + tid;
        s_bias[tid]    = cfold[c]     + dbhh[c];
        s_bias[16+tid] = cfold[256+c] + dbhh[256+c];
        s_bias[32+tid] = cfold[512+c];
        s_dbh[tid]     = dbhh[c];
        s_dbh[16+tid]  = dbhh[256+c];
        s_dbh[32+tid]  = dbhh[512+c];
    }
    if (tid < 4) s_b3[tid] = regb[hb*4 + tid];
    __syncthreads();

    // =================== DECODER ===================
    for (int i = 0; i < TSTEPS; ++i) {
        const int sflag = TSTEPS + i;

        f32x4 aR[2], aZ[2], aNi[2], aNh[2];
        if (wv == 0){
            if (i == 0){
                // gi comes from precomputed gi0 (per-element), bias bhh added
                #pragma unroll
                for (int m = 0; m < 2; ++m){
                    #pragma unroll
                    for (int j = 0; j < 4; ++j){
                        int grow_ = bg*32 + m*16 + quad*4 + j;
                        const float* gp = gi0 + (size_t)grow_*G3 + hcol;
                        aR[m][j]  = gp[0]   + s_dbh[lcol];
                        aZ[m][j]  = gp[256] + s_dbh[16+lcol];
                        aNi[m][j] = gp[512];
                        aNh[m][j] = s_dbh[32+lcol];
                    }
                }
            } else {
                float bR = s_bias[lcol], bZ = s_bias[16+lcol];
                float bNi = s_bias[32+lcol], bNh = s_dbh[32+lcol];
                #pragma unroll
                for (int m = 0; m < 2; ++m){
                    aR[m] = (f32x4){bR,bR,bR,bR}; aZ[m] = (f32x4){bZ,bZ,bZ,bZ};
                    aNi[m] = (f32x4){bNi,bNi,bNi,bNi}; aNh[m] = (f32x4){bNh,bNh,bNh,bNh};
                }
            }
        } else {
            #pragma unroll
            for (int m = 0; m < 2; ++m){ aR[m]=z4; aZ[m]=z4; aNi[m]=z4; aNh[m]=z4; }
        }

        if (tid == POLLER){
            while (load_sys_i32(mycnt + sflag) < HB) __builtin_amdgcn_s_sleep(2);
        }
        __syncthreads();   // B1

        const unsigned* hin = hbuf + (size_t)parity*Bsz*Hsz;
        {
            u32x4 t[8];
            #pragma unroll
            for (int jj = 0; jj < 8; ++jj){
                int flat = (wv*8 + jj)*64 + lane;
                int row = flat >> 6, c4 = flat & 63;
                t[jj] = load_sys_b128u(hin + (size_t)(bg*32+row)*256 + c4*4);
            }
            waitcnt0();
            #pragma unroll
            for (int jj = 0; jj < 8; ++jj) regbar(t[jj]);   // pin unpack after waitcnt
            #pragma unroll
            for (int jj = 0; jj < 8; ++jj){
                int flat = (wv*8 + jj)*64 + lane;
                int row = flat >> 6, c4 = flat & 63;
                u16x4 hh, ll;
                #pragma unroll
                for (int e = 0; e < 4; ++e){
                    unsigned u = t[jj][e];
                    hh[e] = (unsigned short)(u >> 16);
                    ll[e] = (unsigned short)(u & 0xFFFFu);
                }
                *(u16x4*)(s_ah + row*AP + c4*4) = hh;
                *(u16x4*)(s_al + row*AP + c4*4) = ll;
            }
        }
        __syncthreads();   // B2

        // ---- h-MFMA: Whh (gh) and, for i>0, M (gi) on the same A-frags ----
        #pragma unroll
        for (int m = 0; m < 2; ++m){
            #pragma unroll
            for (int q = 0; q < 2; ++q){
                const int ko = wv*64 + q*32 + quad*8;
                s16x8 ah = *(const s16x8*)(s_ah + (m*16+lcol)*AP + ko);
                s16x8 al = *(const s16x8*)(s_al + (m*16+lcol)*AP + ko);
                aR[m]=MF(ah,wfh[0][q],aR[m]); aR[m]=MF(ah,wfl[0][q],aR[m]); aR[m]=MF(al,wfh[0][q],aR[m]);
                aZ[m]=MF(ah,wfh[1][q],aZ[m]); aZ[m]=MF(ah,wfl[1][q],aZ[m]); aZ[m]=MF(al,wfh[1][q],aZ[m]);
                aNh[m]=MF(ah,wfh[2][q],aNh[m]); aNh[m]=MF(ah,wfl[2][q],aNh[m]); aNh[m]=MF(al,wfh[2][q],aNh[m]);
                if (i > 0){
                    aR[m]=MF(ah,mfh[0][q],aR[m]); aR[m]=MF(ah,mfl[0][q],aR[m]); aR[m]=MF(al,mfh[0][q],aR[m]);
                    aZ[m]=MF(ah,mfh[1][q],aZ[m]); aZ[m]=MF(ah,mfl[1][q],aZ[m]); aZ[m]=MF(al,mfh[1][q],aZ[m]);
                    aNi[m]=MF(ah,mfh[2][q],aNi[m]); aNi[m]=MF(ah,mfl[2][q],aNi[m]); aNi[m]=MF(al,mfh[2][q],aNi[m]);
                }
            }
        }

        #pragma unroll
        for (int m = 0; m < 2; ++m){
            f32x4* rp = (f32x4*)s_red + (wv*8 + m*4)*64 + lane;
            rp[0] = aR[m]; rp[64] = aZ[m]; rp[128] = aNi[m]; rp[192] = aNh[m];
        }
        __syncthreads();   // B3

        unsigned* hout = hbuf + (size_t)(parity^1)*Bsz*Hsz;
        if (wv < 2){
            const int m = wv;
            f32x4 R = z4, Z = z4, Ni = z4, Nh = z4;
            #pragma unroll
            for (int w = 0; w < 4; ++w){
                const f32x4* rp = (const f32x4*)s_red + (w*8 + m*4)*64 + lane;
                R += rp[0]; Z += rp[64]; Ni += rp[128]; Nh += rp[192];
            }
            #pragma unroll
            for (int j = 0; j < 4; ++j){
                int rl = m*16 + quad*4 + j;
                float r = sigmoidf_(R[j]);
                float z = sigmoidf_(Z[j]);
                float n = tanhf(Ni[j] + r*Nh[j]);
                float hold = bf16_to_f(s_ah[rl*AP + hcol]) + bf16_to_f(s_al[rl*AP + hcol]);
                float hv = (1.0f - z)*n + z*hold;
                unsigned short p1 = bf16_rne(hv);
                unsigned short p0 = bf16_rne(hv - bf16_to_f(p1));
                store_sys_b32u(hout + (size_t)(bg*32+rl)*256 + hcol,
                               (((unsigned)p1) << 16) | (unsigned)p0);
            }
            waitcnt0();
        } else if (i >= 1){
            // ---- out_{i-1} = H_i @ regW^T + regb, MFMA with N padded 4->16 ----
            const int m = wv - 2;
            float b3 = s_b3[lcol & 3];
            f32x4 oa = (f32x4){b3, b3, b3, b3};
            #pragma unroll
            for (int q8 = 0; q8 < 8; ++q8){
                const int ko = q8*32 + quad*8;
                s16x8 ah = *(const s16x8*)(s_ah + (m*16+lcol)*AP + ko);
                s16x8 al = *(const s16x8*)(s_al + (m*16+lcol)*AP + ko);
                oa = MF(ah, rwh[q8], oa); oa = MF(ah, rwl[q8], oa); oa = MF(al, rwh[q8], oa);
            }
            if (lcol < 4){
                #pragma unroll
                for (int j = 0; j < 4; ++j)
                    out[(size_t)(bg*32 + m*16 + quad*4 + j)*(TSTEPS*Fsz)
                        + (size_t)(i-1)*Fsz + hb*4 + lcol] = oa[j];
            }
        }
        __syncthreads();   // B4
        if (tid == POLLER)
            __hip_atomic_fetch_add(mycnt + sflag + 1, 1, __ATOMIC_RELAXED,
                                   __HIP_MEMORY_SCOPE_SYSTEM);
        parity ^= 1;
    }

    // ---- final out_{127} from H_128 ----
    {
        if (tid == POLLER){
            while (load_sys_i32(mycnt + 2*TSTEPS) < HB) __builtin_amdgcn_s_sleep(2);
        }
        __syncthreads();
        const unsigned* hin = hbuf + (size_t)parity*Bsz*Hsz;
        {
            u32x4 t[8];
            #pragma unroll
            for (int jj = 0; jj < 8; ++jj){
                int flat = (wv*8 + jj)*64 + lane;
                int row = flat >> 6, c4 = flat & 63;
                t[jj] = load_sys_b128u(hin + (size_t)(bg*32+row)*256 + c4*4);
            }
            waitcnt0();
            #pragma unroll
            for (int jj = 0; jj < 8; ++jj) regbar(t[jj]);   // pin unpack after waitcnt
            #pragma unroll
            for (int jj = 0; jj < 8; ++jj){
                int flat = (wv*8 + jj)*64 + lane;
                int row = flat >> 6, c4 = flat & 63;
                u16x4 hh, ll;
                #pragma unroll
                for (int e = 0; e < 4; ++e){
                    unsigned u = t[jj][e];
                    hh[e] = (unsigned short)(u >> 16);
                    ll[e] = (unsigned short)(u & 0xFFFFu);
                }
                *(u16x4*)(s_ah + row*AP + c4*4) = hh;
                *(u16x4*)(s_al + row*AP + c4*4) = ll;
            }
        }
        __syncthreads();
        if (wv >= 2){
            const int m = wv - 2;
            float b3 = s_b3[lcol & 3];
            f32x4 oa = (f32x4){b3, b3, b3, b3};
            #pragma unroll
            for (int q8 = 0; q8 < 8; ++q8){
                const int ko = q8*32 + quad*8;
                s16x8 ah = *(const s16x8*)(s_ah + (m*16+lcol)*AP + ko);
                s16x8 al = *(const s16x8*)(s_al + (m*16+lcol)*AP + ko);
                oa = MF(ah, rwh[q8], oa); oa = MF(ah, rwl[q8], oa); oa = MF(al, rwh[q8], oa);
            }
            if (lcol < 4){
                #pragma unroll
                for (int j = 0; j < 4; ++j)
                    out[(size_t)(bg*32 + m*16 + quad*4 + j)*(TSTEPS*Fsz)
                        + (size_t)(TSTEPS-1)*Fsz + hb*4 + lcol] = oa[j];
            }
        }
    }
}

extern "C" void kernel_launch(void* const* d_in, const int* in_sizes, int n_in,
                              void* d_out, int out_size, void* d_ws, size_t ws_size,
                              hipStream_t stream)
{
    (void)in_sizes; (void)n_in; (void)out_size; (void)ws_size;
    const float* x    = (const float*)d_in[0];
    const float* eWih = (const float*)d_in[1];
    const float* eWhh = (const float*)d_in[2];
    const float* ebih = (const float*)d_in[3];
    const float* ebhh = (const float*)d_in[4];
    const float* dWih = (const float*)d_in[5];
    const float* dWhh = (const float*)d_in[6];
    const float* dbih = (const float*)d_in[7];
    const float* dbhh = (const float*)d_in[8];
    const float* regW = (const float*)d_in[9];
    const float* regb = (const float*)d_in[10];
    float* out = (float*)d_out;

    unsigned* hbuf = (unsigned*)d_ws;                    // 2*512*256 u32 (packed hi/lo bf16)
    float* Mw    = (float*)d_ws + 2*Bsz*Hsz;             // 768*256
    float* gi0   = Mw + G3*Hsz;                          // 512*768
    float* cfold = gi0 + Bsz*G3;                         // 768 (+pad)
    int*   cnt   = (int*)(cfold + 1024);                 // 16*512 ints

    hipMemsetAsync(hbuf, 0, (size_t)Bsz*Hsz*sizeof(unsigned), stream); // h^0 = 0
    hipMemsetAsync(cnt, 0, (size_t)BG*CNT_STRIDE*sizeof(int), stream);

    hipLaunchKernelGGL(gru_setup, dim3(2307), dim3(256), 0, stream,
                       x, dWih, dbih, regW, regb, Mw, cfold, gi0);

    hipFuncSetAttribute((const void*)gru_persistent,
                        hipFuncAttributeMaxDynamicSharedMemorySize, SMEM_BYTES);

    void* args[] = { (void*)&x, (void*)&eWih, (void*)&eWhh, (void*)&ebih, (void*)&ebhh,
                     (void*)&dWhh, (void*)&dbhh, (void*)&Mw, (void*)&cfold, (void*)&gi0,
                     (void*)&regW, (void*)&regb, (void*)&hbuf, (void*)&cnt, (void*)&out };
    hipError_t rc = hipLaunchCooperativeKernel((const void*)gru_persistent,
                                               dim3(NBLK), dim3(NTHR), args,
                                               SMEM_BYTES, stream);
    if (rc != hipSuccess) {
        hipLaunchKernelGGL(gru_persistent, dim3(NBLK), dim3(NTHR), SMEM_BYTES, stream,
                           x, eWih, eWhh, ebih, ebhh, dWhh, dbhh, Mw, cfold, gi0,
                           regW, regb, hbuf, cnt, out);
    }
}